// Round 7
// baseline (281.392 us; speedup 1.0000x reference)
//
#include <hip/hip_runtime.h>

// LSTM encoder B=1024,S=64,H=256 — v7: XCD-local (L2/sc0) tagged h-exchange.
// 32 clusters x 8 WGs x 512 threads (cooperative). Cluster WGs {j*32+cl} share
// bid%8 -> same XCD (heuristic): h exchanged via sc0 (L1-bypass, L2-scope)
// loads/stores of u32{tag16|bf16} — self-validating, tear-proof. Publishers
// also mirror to an agent-scope buffer; readers fall back to it after 48
// failed fast retries (correct under ANY WG->XCD mapping, just slower).
// Weights register-resident (wf[16], pinned). 2 lgkmcnt-only barriers/step.

typedef __attribute__((ext_vector_type(8))) short short8;
typedef __attribute__((ext_vector_type(4))) float f32x4;
typedef unsigned long long u64;
typedef unsigned int u32;
typedef unsigned short u16;

#define B_ 1024
#define S_ 64
#define H_ 256
#define G_ 1024
#define KW 512
#define OUTN (B_*S_*H_)
#define APITCH 520      // A-tile pitch (u16)
#define GPITCH 132      // gates tile pitch (f32)
#define NCL 32
#define CWG 8
#define B128 (B_*128)   // u64 slots (2 elems each) per parity buffer

__device__ __forceinline__ u16 f2bf(float f){
    u32 u = __builtin_bit_cast(u32, f);
    u = (u + 0x7fffu + ((u >> 16) & 1u)) >> 16;   // RNE
    return (u16)u;
}
__device__ __forceinline__ float sigm(float v){ return 1.0f/(1.0f + __expf(-v)); }
__device__ __forceinline__ float tanh_(float v){ return 2.0f/(1.0f + __expf(-2.0f*v)) - 1.0f; }

// L2-scope (XCD-local) 8B store/load: sc0 = L1-bypass, served by L2.
__device__ __forceinline__ void st_l2_x2(u64* p, u64 v){
    asm volatile("global_store_dwordx2 %0, %1, off sc0" :: "v"(p), "v"(v) : "memory");
}
__device__ __forceinline__ void ld_l2_x2(u64* dst, const u64* p){
    asm volatile("global_load_dwordx2 %0, %1, off sc0" : "=v"(*dst) : "v"(p) : "memory");
}
__device__ __forceinline__ void wait_vm0(){
    asm volatile("s_waitcnt vmcnt(0)" ::: "memory");
    __builtin_amdgcn_sched_barrier(0);
}
// raw workgroup barrier: waits LDS ops only (no vmcnt drain)
__device__ __forceinline__ void wg_barrier_lds(){
    asm volatile("s_waitcnt lgkmcnt(0)" ::: "memory");
    __builtin_amdgcn_sched_barrier(0);
    __builtin_amdgcn_s_barrier();
    __builtin_amdgcn_sched_barrier(0);
}

__global__ __launch_bounds__(256) void prep_kernel(const float* __restrict__ Wih,
        const float* __restrict__ Whh, const float* __restrict__ bih,
        const float* __restrict__ bhh, const float* __restrict__ h0,
        u16* __restrict__ Wc, float* __restrict__ bias,
        u64* __restrict__ hqf, u64* __restrict__ hqs){
    int idx = blockIdx.x*256 + threadIdx.x;
    if (idx < G_*KW){
        int g = idx >> 9, k = idx & 511;
        float v = (k < H_) ? Wih[g*H_ + k] : Whh[g*H_ + (k - H_)];
        Wc[idx] = f2bf(v);
    }
    if (idx < G_) bias[idx] = bih[idx] + bhh[idx];
    if (idx < B128){
        int b = idx >> 7, c = idx & 127;
        u32 plo = (u32)f2bf(h0[b*H_ + 2*c]);        // tag 0
        u32 phi = (u32)f2bf(h0[b*H_ + 2*c + 1]);    // tag 0
        u64 v = ((u64)phi << 32) | plo;
        hqf[idx] = v;                hqs[idx] = v;               // parity 0: h(0)
        hqf[B128 + idx] = 0xFFFF0000FFFF0000ull;                 // parity 1: stale
        hqs[B128 + idx] = 0xFFFF0000FFFF0000ull;
    }
}

__global__ __launch_bounds__(512, 2) void lstm_kernel(
        const float* __restrict__ x, const float* __restrict__ c0,
        const u16* __restrict__ Wc, const float* __restrict__ bias,
        u64* hqf, u64* hqs, float* __restrict__ out){
    __shared__ u16 At[32*APITCH];    // [batch][k: 0..255=x, 256..511=h]
    __shared__ float Gt[32*GPITCH];  // [batch][128 gate cols]

    const int tid  = threadIdx.x;
    const int lane = tid & 63;
    const int w    = tid >> 6;
    const int wn   = w >> 1, tn = w & 1;
    const int nl   = lane & 15, kg = lane >> 4;
    const int bid  = blockIdx.x;
    const int cl   = bid & (NCL-1);
    const int j    = bid >> 5;        // wg-in-cluster 0..7 (bid%8 == cl%8 -> same XCD)
    const int b0   = cl * 32;
    const int d0   = j * 32;

    // ---- persistent W: wave holds 16 gate rows ----
    const int grow_idx = wn*256 + d0 + tn*16 + nl;
    short8 wf[16];
    {
        const u16* wp = Wc + (size_t)grow_idx*KW + kg*8;
        #pragma unroll
        for (int kf = 0; kf < 16; ++kf) wf[kf] = *(const short8*)(wp + kf*32);
    }
    #pragma unroll
    for (int kf = 0; kf < 16; ++kf) asm volatile("" : "+v"(wf[kf]));  // pin
    const float bias_l = bias[grow_idx];

    // ---- per-thread roles ----
    const int sb = tid >> 4;          // batch 0..31
    const int dp = tid & 15;          // dim pair / staging col / gather lane
    float c0r, c1r;
    {
        float2 cv = *(const float2*)(c0 + (size_t)(b0+sb)*H_ + d0 + 2*dp);
        c0r = cv.x; c1r = cv.y;
    }

    // remote chunk table: 112 u64 slots (2 dims each), skipping own [16j,16j+16)
    int rc[7];
    #pragma unroll
    for (int i = 0; i < 7; ++i){
        int m = i*16 + dp;
        rc[i] = m + (m >= 16*j ? 16 : 0);
    }

    // ---- prologue: stage x(0) + h(0); prefetch x(1) ----
    float xr[16];
    {
        const float* xp = x + ((size_t)(b0+sb)*S_ + 0)*H_ + dp*16;
        #pragma unroll
        for (int q = 0; q < 4; ++q){
            f32x4 v = *(const f32x4*)(xp + q*4);
            xr[q*4+0]=v[0]; xr[q*4+1]=v[1]; xr[q*4+2]=v[2]; xr[q*4+3]=v[3];
        }
        u16 tmp[16];
        #pragma unroll
        for (int q = 0; q < 16; ++q) tmp[q] = f2bf(xr[q]);
        *(short8*)(At + sb*APITCH + dp*16)     = *(const short8*)tmp;
        *(short8*)(At + sb*APITCH + dp*16 + 8) = *(const short8*)(tmp+8);
    }
    {
        const u64* hb = hqf + (size_t)(b0+sb)*128;    // parity 0, kernel-boundary coherent
        #pragma unroll
        for (int i = 0; i < 8; ++i){
            int c = dp + 16*i;
            u64 v = hb[c];
            u32 lo = (u32)v, hi = (u32)(v >> 32);
            *(u32*)(At + sb*APITCH + H_ + 2*c) = (lo & 0xFFFFu) | (hi << 16);
        }
    }
    {
        const float* xp = x + ((size_t)(b0+sb)*S_ + 1)*H_ + dp*16;
        #pragma unroll
        for (int q = 0; q < 4; ++q){
            f32x4 v = *(const f32x4*)(xp + q*4);
            xr[q*4+0]=v[0]; xr[q*4+1]=v[1]; xr[q*4+2]=v[2]; xr[q*4+3]=v[3];
        }
    }
    __syncthreads();

    u64 gv[7] = {};                   // in-flight gather values (tagged)
    bool slowmode = false;            // agent-scope fallback (wrong XCD mapping)

    #pragma unroll 1
    for (int s = 0; s < S_; ++s){
        // ---- B: x-part MFMA (frames 0..7) — gather loads fly underneath ----
        f32x4 acc0 = (f32x4){bias_l, bias_l, bias_l, bias_l};
        f32x4 acc1 = acc0;
        const u16* ar = At + nl*APITCH + kg*8;
        #pragma unroll
        for (int kf = 0; kf < 8; ++kf){
            short8 a0 = *(const short8*)(ar + kf*32);
            short8 a1 = *(const short8*)(ar + 16*APITCH + kf*32);
            acc0 = __builtin_amdgcn_mfma_f32_16x16x32_bf16(a0, wf[kf], acc0, 0, 0, 0);
            acc1 = __builtin_amdgcn_mfma_f32_16x16x32_bf16(a1, wf[kf], acc1, 0, 0, 0);
        }

        // ---- C: validate gather tags (retry via L2; fallback agent) ----
        if (s > 0){
            const u32 want = (u32)s;
            const u64* gfb = hqf + (size_t)(s & 1)*B128 + (size_t)(b0+sb)*128;
            const u64* gsb = hqs + (size_t)(s & 1)*B128 + (size_t)(b0+sb)*128;
            wait_vm0();
            int guard = 0;
            for (;;){
                bool ok = true;
                #pragma unroll
                for (int i = 0; i < 7; ++i){
                    u32 lo = (u32)gv[i], hi = (u32)(gv[i] >> 32);
                    ok = ok && ((lo >> 16) == want) && ((hi >> 16) == want);
                }
                if (__all((int)ok)) break;
                if (++guard > (1<<13)) break;      // fail loud, never hang
                if (guard >= 48) slowmode = true;
                if (!slowmode){
                    #pragma unroll
                    for (int i = 0; i < 7; ++i) ld_l2_x2(&gv[i], gfb + rc[i]);
                    wait_vm0();
                } else {
                    #pragma unroll
                    for (int i = 0; i < 7; ++i)
                        gv[i] = __hip_atomic_load(gsb + rc[i], __ATOMIC_RELAXED,
                                                  __HIP_MEMORY_SCOPE_AGENT);
                }
            }
            #pragma unroll
            for (int i = 0; i < 7; ++i){
                u32 lo = (u32)gv[i], hi = (u32)(gv[i] >> 32);
                *(u32*)(At + sb*APITCH + H_ + 2*rc[i]) = (lo & 0xFFFFu) | (hi << 16);
            }
        }
        wg_barrier_lds();   // barrier#1: At h-cols complete

        // ---- E: h-part MFMA (frames 8..15) ----
        #pragma unroll
        for (int kf = 8; kf < 16; ++kf){
            short8 a0 = *(const short8*)(ar + kf*32);
            short8 a1 = *(const short8*)(ar + 16*APITCH + kf*32);
            acc0 = __builtin_amdgcn_mfma_f32_16x16x32_bf16(a0, wf[kf], acc0, 0, 0, 0);
            acc1 = __builtin_amdgcn_mfma_f32_16x16x32_bf16(a1, wf[kf], acc1, 0, 0, 0);
        }

        // ---- F: restage x(s+1); Gt stores ----
        if (s + 1 < S_){
            u16 tmp[16];
            #pragma unroll
            for (int q = 0; q < 16; ++q) tmp[q] = f2bf(xr[q]);
            *(short8*)(At + sb*APITCH + dp*16)     = *(const short8*)tmp;
            *(short8*)(At + sb*APITCH + dp*16 + 8) = *(const short8*)(tmp+8);
        }
        {
            const int colc = wn*32 + tn*16 + nl;
            #pragma unroll
            for (int jj = 0; jj < 4; ++jj){
                Gt[(kg*4 + jj)*GPITCH + colc]      = acc0[jj];   // batches 0..15
                Gt[(16 + kg*4 + jj)*GPITCH + colc] = acc1[jj];   // batches 16..31
            }
        }
        wg_barrier_lds();   // barrier#2: Gt + x-restage complete

        // ---- G: cell; publish tagged h (fast sc0 + slow agent); out; prefetch ----
        {
            const float* gr = Gt + sb*GPITCH + 2*dp;
            float iv0 = gr[0],  iv1 = gr[1];
            float fv0 = gr[32], fv1 = gr[33];
            float gv0 = gr[64], gv1 = gr[65];
            float ov0 = gr[96], ov1 = gr[97];
            float cn0 = sigm(fv0)*c0r + sigm(iv0)*tanh_(gv0);
            float cn1 = sigm(fv1)*c1r + sigm(iv1)*tanh_(gv1);
            float hn0 = sigm(ov0)*tanh_(cn0);
            float hn1 = sigm(ov1)*tanh_(cn1);
            c0r = cn0; c1r = cn1;

            if (s < S_-1){
                u32 t16 = (u32)(s+1) << 16;
                u32 plo = t16 | (u32)f2bf(hn0);
                u32 phi = t16 | (u32)f2bf(hn1);
                u64 pv  = ((u64)phi << 32) | plo;
                size_t slot = (size_t)((s+1)&1)*B128 + (size_t)(b0+sb)*128 + (d0>>1) + dp;
                st_l2_x2(hqf + slot, pv);                       // fast: XCD L2
                __hip_atomic_store(hqs + slot, pv,              // slow: coherence point
                                   __ATOMIC_RELAXED, __HIP_MEMORY_SCOPE_AGENT);
                u32 hpk = (u32)f2bf(hn0) | ((u32)f2bf(hn1) << 16);
                *(u32*)(At + sb*APITCH + H_ + d0 + 2*dp) = hpk; // own slice
            }
            size_t o = ((size_t)(b0+sb)*S_ + s)*H_ + d0 + 2*dp;
            float2 hv; hv.x = hn0; hv.y = hn1;
            *(float2*)(out + o) = hv;
            *(float2*)(out + OUTN + o) = hv;
        }
        if (s + 1 < S_){
            const u64* gfb = hqf + (size_t)((s+1)&1)*B128 + (size_t)(b0+sb)*128;
            #pragma unroll
            for (int i = 0; i < 7; ++i) ld_l2_x2(&gv[i], gfb + rc[i]);
        }
        if (s + 2 < S_){
            const float* xp = x + ((size_t)(b0+sb)*S_ + (s+2))*H_ + dp*16;
            #pragma unroll
            for (int q = 0; q < 4; ++q){
                f32x4 v = *(const f32x4*)(xp + q*4);
                xr[q*4+0]=v[0]; xr[q*4+1]=v[1]; xr[q*4+2]=v[2]; xr[q*4+3]=v[3];
            }
        }
    }
}

extern "C" void kernel_launch(void* const* d_in, const int* in_sizes, int n_in,
                              void* d_out, int out_size, void* d_ws, size_t ws_size,
                              hipStream_t stream){
    const float* x   = (const float*)d_in[0];
    const float* h0  = (const float*)d_in[1];
    const float* c0  = (const float*)d_in[2];
    const float* Wih = (const float*)d_in[3];
    const float* Whh = (const float*)d_in[4];
    const float* bih = (const float*)d_in[5];
    const float* bhh = (const float*)d_in[6];

    u16*   Wc   = (u16*)d_ws;                          // 1 MB @ 0
    float* bias = (float*)((char*)d_ws + 0x100000);    // 4 KB
    u64*   hqf  = (u64*)((char*)d_ws + 0x110000);      // 2 MB fast (L2-scope)
    u64*   hqs  = (u64*)((char*)d_ws + 0x310000);      // 2 MB slow (agent-scope)
    float* outp = (float*)d_out;

    prep_kernel<<<(G_*KW + 255)/256, 256, 0, stream>>>(Wih, Whh, bih, bhh, h0,
                                                       Wc, bias, hqf, hqs);

    void* args[] = {(void*)&x, (void*)&c0, (void*)&Wc, (void*)&bias,
                    (void*)&hqf, (void*)&hqs, (void*)&outp};
    hipLaunchCooperativeKernel((void*)lstm_kernel, dim3(NCL*CWG), dim3(512), args, 0, stream);
}